// Round 15
// baseline (3579.636 us; speedup 1.0000x reference)
//
#include <hip/hip_runtime.h>
#include <math.h>
#include <stdint.h>

// Problem constants
#define DD 500
#define BB 512
// Permuted N layout: slab s (0..63) owns cols [32s, 32s+32) = [r|z|i_n|h_n]
// for d in [8s, 8s+8).  r/z cols hold x@(Wih+Whh) for t>=1 (x==h); t=0 uses
// Wp0 (Wih only in r/z).
// Split-precision: C = Ah·Wh + Al·Wh + Ah·Wl.  Wp k-order: [Wh|Wh|Wl]
// (wksteps 0..31 Wh(x Ah), 32..63 Wh(x Al), 64..95 Wl(x Ah)).
// Ap holds [Ah|Al] (64 ksteps, K=1024).
#define NSTRIPS 64     // n-strips (slabs) of 32
#define MSTRIPS 16     // m-strips of 32
#define WKSTEPS 96     // Wp ksteps of 16
#define AKSTEPS 64     // Ap ksteps of 16 ([Ah|Al])
#define NELEM (BB*DD)
// Persistent grid: 8 row-groups (64 rows) x 32 col-groups (2 slabs, 16 d)
// = 256 blocks x 1024 threads (16 waves = m-half x K-eighth; per-wave serial
// B chain = 12 ksteps, 4 waves/SIMD TLP). bid%8 = cg%8 -> blocks sharing a
// B slice land on one XCD.
#define GRG 8
#define GCG 32
#define NBLK 256
#define HSTRIDE 1024   // floats per (block, hist slot): 64 rows x 16 d

typedef _Float16 f16;
typedef _Float16 f16x8 __attribute__((ext_vector_type(8)));
typedef float    f32x16 __attribute__((ext_vector_type(16)));
typedef unsigned u32x4  __attribute__((ext_vector_type(4)));

#define APCNT ((size_t)MSTRIPS * AKSTEPS * 64 * 8)  // f16 per Ap buffer (1MB)
#define WPCNT ((size_t)NSTRIPS * WKSTEPS * 64 * 8)  // f16 per Wp buffer

// Fragment-order layout (Ap and Wp):
//   elem(strip, kstep, ln, j) at ((strip*KS + kstep)*64 + ln)*8 + j
//   row = strip*32 + (ln&31),  k = kstep*16 + (ln>>5)*8 + j
// = the mfma_f32_32x32x16_f16 A/B operand layout.

__device__ __forceinline__ float aload_f32(const float* p) {
    return __hip_atomic_load(p, __ATOMIC_RELAXED, __HIP_MEMORY_SCOPE_AGENT);
}
// Coalesced device-scope 16B load/store (sc0 sc1: served at the device
// coherence point). Used ONLY with an immediate vmcnt(0) drain.
__device__ __forceinline__ void aload16i(u32x4& d, const f16* p) {
    asm volatile("global_load_dwordx4 %0, %1, off sc0 sc1"
                 : "=&v"(d) : "v"(p) : "memory");
}
__device__ __forceinline__ void astore16(f16* p, u32x4 v) {
    asm volatile("global_store_dwordx4 %0, %1, off sc0 sc1"
                 :: "v"(p), "v"(v) : "memory");
}

// fast sigmoid/tanh via hardware v_exp: rel err ~1e-6
__device__ __forceinline__ float fsigmoid(float x) {
    return 1.0f / (1.0f + __expf(-x));
}
__device__ __forceinline__ float ftanh(float x) {
    return 2.0f / (1.0f + __expf(-2.0f * x)) - 1.0f;
}

// ---------------------------------------------------------------------------
// Wp0 (t=0) and Wp1 (t>=1), frag order, PERMUTED cols. k-blocks: [Wh|Wh|Wl].
// ---------------------------------------------------------------------------
__global__ __launch_bounds__(256) void conv_w(const float* __restrict__ Wih,
                                              const float* __restrict__ Whh,
                                              f16* __restrict__ Wp0,
                                              f16* __restrict__ Wp1)
{
    int p = blockIdx.x * 256 + threadIdx.x;    // (strip, kstep, ln)
    const int ln = p & 63; p >>= 6;
    const int kstep = p % WKSTEPS;
    const int strip = p / WKSTEPS;             // slab s, 0..63
    const int q = ln & 31;                     // col within slab
    const int g = q >> 3;                      // 0 r, 1 z, 2 i_n, 3 h_n
    const int d = strip * 8 + (q & 7);         // 0..511
    const int kb0 = kstep * 16 + (ln >> 5) * 8;
    const int blk = kb0 >> 9, bk0 = kb0 & 511;
    const float* pih = 0;
    const float* phh = 0;
    if (d < DD) {
        if (g == 0)      { pih = Wih + (size_t)d * DD;
                           phh = Whh + (size_t)d * DD; }
        else if (g == 1) { pih = Wih + (size_t)(500 + d) * DD;
                           phh = Whh + (size_t)(500 + d) * DD; }
        else if (g == 2) { pih = Wih + (size_t)(1000 + d) * DD; }
        else             { phh = Whh + (size_t)(1000 + d) * DD; }
    }
    f16 o0[8], o1[8];
    #pragma unroll
    for (int j = 0; j < 8; ++j) {
        const int bk = bk0 + j;
        float vi = 0.f, vh = 0.f;
        if (bk < DD) {
            if (pih) vi = pih[bk];
            if (phh) vh = phh[bk];
        }
        const float v0 = (g == 3) ? vh : vi;           // Wp0 value
        const float v1 = (g <= 1) ? (vi + vh) : v0;    // Wp1 value
        f16 h0 = (f16)v0;
        f16 h1 = (f16)v1;
        o0[j] = (blk == 2) ? (f16)(v0 - (float)h0) : h0;
        o1[j] = (blk == 2) ? (f16)(v1 - (float)h1) : h1;
    }
    const size_t off = ((size_t)(strip * WKSTEPS + kstep) * 64 + ln) * 8;
    *(uint4*)(Wp0 + off) = *(uint4*)o0;
    *(uint4*)(Wp1 + off) = *(uint4*)o1;
}

// ---------------------------------------------------------------------------
// Ap buffer 0 (frag order) from initial state. k-blocks: [Ah | Al], K=1024
// ---------------------------------------------------------------------------
__global__ __launch_bounds__(256) void conv_a(const float* __restrict__ S,
                                              f16* __restrict__ Ap)
{
    int p = blockIdx.x * 256 + threadIdx.x;    // (mstrip, kstep, ln)
    const int ln = p & 63; p >>= 6;
    const int kstep = p % AKSTEPS;
    const int strip = p / AKSTEPS;             // 0..15
    const int b = strip * 32 + (ln & 31);
    const int kb0 = kstep * 16 + (ln >> 5) * 8;
    const int blk = kb0 >> 9, bk0 = kb0 & 511;
    f16 out[8];
    #pragma unroll
    for (int j = 0; j < 8; ++j) {
        const int bk = bk0 + j;
        float v = (bk < DD) ? S[(size_t)b * DD + bk] : 0.f;
        f16 hi = (f16)v;
        out[j] = (blk == 1) ? (f16)(v - (float)hi) : hi;
    }
    *(uint4*)(Ap + ((size_t)(strip * AKSTEPS + kstep) * 64 + ln) * 8) = *(uint4*)out;
}

// ---------------------------------------------------------------------------
// Device-wide two-level barrier (once per 8-iter WINDOW only). Monotone,
// relaxed AGENT atomics. 32 groups of 8 blocks: bar[g*16] (64B apart),
// bar[512] root (32 arrivals), bar[528] generation.
// ---------------------------------------------------------------------------
__device__ __forceinline__ void grid_sync(unsigned* bar, unsigned e)
{
    __syncthreads();
    if (threadIdx.x == 0) {
        unsigned* gcnt = bar + ((blockIdx.x >> 3) << 4);
        unsigned* root = bar + 512;
        unsigned* gen  = bar + 528;
        unsigned a = __hip_atomic_fetch_add(gcnt, 1u, __ATOMIC_RELAXED,
                                            __HIP_MEMORY_SCOPE_AGENT);
        if (a == e * 8u + 7u) {
            unsigned r = __hip_atomic_fetch_add(root, 1u, __ATOMIC_RELAXED,
                                                __HIP_MEMORY_SCOPE_AGENT);
            if (r == e * 32u + 31u) {
                __hip_atomic_store(gen, e + 1u, __ATOMIC_RELAXED,
                                   __HIP_MEMORY_SCOPE_AGENT);
            } else {
                while (__hip_atomic_load(gen, __ATOMIC_RELAXED,
                                         __HIP_MEMORY_SCOPE_AGENT) <= e)
                    __builtin_amdgcn_s_sleep(1);
            }
        } else {
            while (__hip_atomic_load(gen, __ATOMIC_RELAXED,
                                     __HIP_MEMORY_SCOPE_AGENT) <= e)
                __builtin_amdgcn_s_sleep(1);
        }
    }
    __syncthreads();
}

// ---------------------------------------------------------------------------
// Persistent fused kernel, 256 blocks x 1024 threads (16 waves = m-half x
// K-eighth). Block = 64 rows x 2 slabs x full K. Per-wave chain 12 ksteps;
// 4 waves/SIMD hide the sunk B-loads.
// Per iter: prefill phase-H B | group wait | stage Ah chunk + issue Al loads
// | phase-H MFMA (8 ksteps: Wh & Wl against Ah) | prefill phase-L B |
// restage Al | phase-L MFMA (4 ksteps) | Ct 2-round combine (kq0 write,
// kq>0 LDS atomicAdd) | EW (1 elem/thread, h in reg) | pack (sc stores) |
// group signal. Grid sync + break scan every 8 iters (speculative, 8-deep
// h history ring). LDS 64KB time-multiplexed: A chunk; then Ct/hbufP/red.
// ---------------------------------------------------------------------------
__global__ __launch_bounds__(1024, 1) void gru_persist(
    f16* __restrict__ ApB,                 // 2 buffers of APCNT
    const f16* __restrict__ Wp0, const f16* __restrict__ Wp1,
    const float* __restrict__ bih, const float* __restrict__ bhh,
    float* __restrict__ out, float* __restrict__ spart,  // [8][64] stride 64
    const float* __restrict__ bc, const int* __restrict__ rec,
    unsigned* __restrict__ bar, unsigned* __restrict__ garr,
    float* __restrict__ hist)
{
    const int bid = blockIdx.x;
    const int tid = threadIdx.x;
    const int rounds = min(64, rec[0]);
    if (rounds <= 0) return;               // uniform: no barriers entered
    const float thr = bc[0] * (float)NELEM;

    const int cg = bid & 31;               // col-group (d base = 16*cg)
    const int rg = bid >> 5;               // row-group (64 rows)
    const int wv = tid >> 6, ln = tid & 63;
    const int mh = wv >> 3;                // m-half (32 rows)
    const int kq = wv & 7;                 // K-eighth
    const int sb0 = cg * 2, sb1 = cg * 2 + 1;          // this block's slabs

    __shared__ __align__(16) char smem[65536];
    f16*      Alds  = (f16*)smem;                      // [2 sl][32 aks][64][8]
    float*    Ct    = (float*)smem;                    // [64][2 sl][4 g][9]
    unsigned* hbufP = (unsigned*)(smem + 20480);       // [64][17] hi|lo pack
    float*    red   = (float*)(smem + 24832);          // [16]
    int*      trig  = (int*)(smem + 24896);

    float h0r = 0.0f;                      // registered h state (1/thread)

    f16* bufs0 = ApB;
    f16* bufs1 = ApB + APCNT;
    unsigned* gptr = garr + rg * 16;       // group counter (own 64B line)
    unsigned wep = 0;                      // grid-sync episode

    for (int t = 0; t < rounds; ++t) {
        const f16* Wb    = (t == 0) ? Wp0 : Wp1;
        const f16* Abase = (t & 1) ? bufs1 : bufs0;
        f16*       Apw   = (t & 1) ? bufs0 : bufs1;    // EW writes other buf
        const f16* Bb0   = Wb + (size_t)sb0 * WKSTEPS * 512 + (size_t)ln * 8;
        const f16* Bb1   = Wb + (size_t)sb1 * WKSTEPS * 512 + (size_t)ln * 8;

        // phase-H B prefill: wk = kq*4+i (i<4) and 64+kq*4+(i-4) (i>=4)
        uint4 rH0[8], rH1[8];
        #pragma unroll
        for (int i = 0; i < 8; ++i) {
            const int wk = (i < 4) ? (kq * 4 + i) : (64 + kq * 4 + (i - 4));
            rH0[i] = *(const uint4*)(Bb0 + (size_t)wk * 512);
            rH1[i] = *(const uint4*)(Bb1 + (size_t)wk * 512);
        }
        // group wait: all 32 producers of our A rows finished EW(t-1)
        if (t > 0) {
            if (tid == 0) {
                while (__hip_atomic_load(gptr, __ATOMIC_RELAXED,
                                         __HIP_MEMORY_SCOPE_AGENT)
                       < 32u * (unsigned)t)
                    __builtin_amdgcn_s_sleep(1);
            }
            __syncthreads();
        }

        // stage chunk H (Ah: aks 0..31, strips 2rg,2rg+1): 4 x 16B sc / thr
        u32x4 av[4];
        #pragma unroll
        for (int i = 0; i < 4; ++i) {
            const int flat = tid + 1024 * i;           // 16B units
            const int sl_ = flat >> 11, rem = flat & 2047;
            aload16i(av[i], Abase +
                ((size_t)((2 * rg + sl_) * AKSTEPS + (rem >> 6)) * 64
                 + (rem & 63)) * 8);
        }
        asm volatile("s_waitcnt vmcnt(0)" ::: "memory");
        __builtin_amdgcn_sched_barrier(0);
        #pragma unroll
        for (int i = 0; i < 4; ++i)
            *(u32x4*)(Alds + (size_t)(tid + 1024 * i) * 8) = av[i];
        // issue chunk L (Al: aks 32..63) loads NOW: latency hides under
        // phase-H MFMA (registers held across the phase)
        #pragma unroll
        for (int i = 0; i < 4; ++i) {
            const int flat = tid + 1024 * i;
            const int sl_ = flat >> 11, rem = flat & 2047;
            aload16i(av[i], Abase +
                ((size_t)((2 * rg + sl_) * AKSTEPS + 32 + (rem >> 6)) * 64
                 + (rem & 63)) * 8);
        }
        __syncthreads();

        // phase H: 8 ksteps/wave (Ah x Wh, Ah x Wl). ka = kq*4 + (ksl&3).
        f32x16 acc0 = {}, acc1 = {};
        #pragma unroll
        for (int ksl = 0; ksl < 8; ++ksl) {
            const int ka = kq * 4 + (ksl & 3);
            f16x8 a = *(const f16x8*)(Alds + ((size_t)(mh * 32 + ka) * 512
                                              + (size_t)ln * 8));
            acc0 = __builtin_amdgcn_mfma_f32_32x32x16_f16(
                       a, *(f16x8*)&rH0[ksl], acc0, 0, 0, 0);
            acc1 = __builtin_amdgcn_mfma_f32_32x32x16_f16(
                       a, *(f16x8*)&rH1[ksl], acc1, 0, 0, 0);
        }
        // phase-L B prefill: wk = 32 + kq*4 + i
        uint4 rL0[4], rL1[4];
        #pragma unroll
        for (int i = 0; i < 4; ++i) {
            rL0[i] = *(const uint4*)(Bb0 + (size_t)(32 + kq * 4 + i) * 512);
            rL1[i] = *(const uint4*)(Bb1 + (size_t)(32 + kq * 4 + i) * 512);
        }
        __syncthreads();                   // phase-H A reads done

        // restage chunk L into the same buffer
        asm volatile("s_waitcnt vmcnt(0)" ::: "memory");
        __builtin_amdgcn_sched_barrier(0);
        #pragma unroll
        for (int i = 0; i < 4; ++i)
            *(u32x4*)(Alds + (size_t)(tid + 1024 * i) * 8) = av[i];
        __syncthreads();

        // phase L: 4 ksteps/wave (Al x Wh)
        #pragma unroll
        for (int ksl = 0; ksl < 4; ++ksl) {
            const int ka = kq * 4 + ksl;
            f16x8 a = *(const f16x8*)(Alds + ((size_t)(mh * 32 + ka) * 512
                                              + (size_t)ln * 8));
            acc0 = __builtin_amdgcn_mfma_f32_32x32x16_f16(
                       a, *(f16x8*)&rL0[ksl], acc0, 0, 0, 0);
            acc1 = __builtin_amdgcn_mfma_f32_32x32x16_f16(
                       a, *(f16x8*)&rL1[ksl], acc1, 0, 0, 0);
        }
        __syncthreads();                   // all MFMA done; A buffer dead

        // Ct combine, 2 rounds. C/D layout: col=lane&31,
        // row=(r&3)+8*(r>>2)+4*(lane>>5). Ct addr = row*72 + sl*36 + g*9 + dd
        {
            const int q = ln & 31, g = q >> 3, dd = q & 7;
            if (kq == 0) {
                #pragma unroll
                for (int r = 0; r < 16; ++r) {
                    const int row = mh * 32 + (r & 3) + 8 * (r >> 2)
                                    + 4 * (ln >> 5);
                    float* c0 = Ct + row * 72 + g * 9 + dd;
                    c0[0]  = acc0[r];
                    c0[36] = acc1[r];
                }
            }
            __syncthreads();
            if (kq != 0) {
                #pragma unroll
                for (int r = 0; r < 16; ++r) {
                    const int row = mh * 32 + (r & 3) + 8 * (r >> 2)
                                    + 4 * (ln >> 5);
                    float* c0 = Ct + row * 72 + g * 9 + dd;
                    atomicAdd(c0,      acc0[r]);
                    atomicAdd(c0 + 36, acc1[r]);
                }
            }
            __syncthreads();
        }

        // ---------------- EW phase (1 elem/thread, h in reg) --------------
        float* hw = hist + ((size_t)bid * 8 + (size_t)(t & 7)) * HSTRIDE;
        float psum = 0.0f;
        {
            const int row = tid >> 4, dl = tid & 15;
            const int d = cg * 16 + dl;
            const int sl = dl >> 3, dd = dl & 7;
            float hnew = 0.0f;
            if (d < DD) {
                const float* cb = &Ct[row * 72 + sl * 36 + dd];
                float cr = cb[0], cz = cb[9], cin = cb[18], chn = cb[27];
                float r = fsigmoid(cr + bih[d] + bhh[d]);
                float z = fsigmoid(cz + bih[500 + d] + bhh[500 + d]);
                float inn = cin + bih[1000 + d];
                float hn  = bhh[1000 + d];
                float hp  = 0.0f;
                if (t > 0) { hn += chn; hp = h0r; }
                float n = ftanh(inn + r * hn);
                hnew = (1.0f - z) * n + z * hp;
                psum = hnew;
            }
            h0r = hnew;
            hw[tid] = hnew;                    // history ring (block-private)
            f16 hi = (f16)hnew;
            f16 lo = (f16)(hnew - (float)hi);
            union { f16 f[2]; unsigned u; } pk;
            pk.f[0] = hi; pk.f[1] = lo;
            hbufP[row * 17 + dl] = pk.u;       // pad-striped
        }
        // block reduce psum -> spart shard (cg&7)
        #pragma unroll
        for (int off = 32; off > 0; off >>= 1) psum += __shfl_down(psum, off, 64);
        if (ln == 0) red[wv] = psum;
        __syncthreads();                        // red + hbufP ready
        if (tid == 0) {
            float v = 0.f;
            #pragma unroll
            for (int i = 0; i < 16; ++i) v += red[i];
            __hip_atomic_fetch_add(&spart[(size_t)(cg & 7) * 64 + t], v,
                                   __ATOMIC_RELAXED, __HIP_MEMORY_SCOPE_AGENT);
        }
        // pack Ap: (row 0..63, oct 0..1) -> d0 = cg*16 + oct*8.
        // hi kstep = cg, lo kstep = 32+cg, half = oct, strip = 2rg + row/32.
        if (tid < 128) {
            const int row = tid >> 1, oct = tid & 1;
            union { f16 a[8]; u32x4 v; } hiU, loU;
            #pragma unroll
            for (int j = 0; j < 8; ++j) {
                unsigned u = hbufP[row * 17 + oct * 8 + j];
                union { unsigned u; f16 f[2]; } pk; pk.u = u;
                hiU.a[j] = pk.f[0];
                loU.a[j] = pk.f[1];
            }
            const int strip = 2 * rg + (row >> 5), lm = row & 31;
            f16* dhi = Apw + ((size_t)(strip * AKSTEPS + cg)      * 64
                              + oct * 32 + lm) * 8;
            f16* dlo = Apw + ((size_t)(strip * AKSTEPS + 32 + cg) * 64
                              + oct * 32 + lm) * 8;
            astore16(dhi, hiU.v);
            astore16(dlo, loU.v);
        }
        asm volatile("s_waitcnt vmcnt(0)" ::: "memory");   // sc stores acked
        __syncthreads();
        if (tid == 0)
            __hip_atomic_fetch_add(gptr, 1u, __ATOMIC_RELAXED,
                                   __HIP_MEMORY_SCOPE_AGENT);

        // -------- window boundary: grid sync + break scan -----------------
        if (((t & 7) == 7) || (t == rounds - 1)) {
            grid_sync(bar, wep++);             // all spart(t' <= t) visible
            if (tid < 64) {                    // wave 0 scans the window
                const int cgl = tid & 7, ti = tid >> 3;
                const int tt = (t & ~7) + ti;
                float v = 0.f;
                if (tt <= t)
                    v = aload_f32(&spart[(size_t)cgl * 64 + tt]);
                v += __shfl_xor(v, 1, 64);
                v += __shfl_xor(v, 2, 64);
                v += __shfl_xor(v, 4, 64);
                bool hit = ((tid & 7) == 0) && (tt <= t) && (v > thr);
                unsigned long long m = __ballot(hit);
                if (tid == 0)
                    trig[0] = m ? (int)((__ffsll((long long)m) - 1) >> 3) : -1;
            }
            __syncthreads();
            const int w0 = trig[0];
            if (w0 >= 0) {                     // break fired at ts (uniform)
                const int ts = (t & ~7) + w0;
                const float* hs = hist
                    + ((size_t)bid * 8 + (size_t)(ts & 7)) * HSTRIDE;
                const int row = tid >> 4, dl = tid & 15;
                const int d = cg * 16 + dl;
                if (d < DD)
                    out[(size_t)(rg * 64 + row) * DD + d] = hs[tid];
                return;
            }
        }
    }

    // no trigger: final output from registered h
    {
        const int row = tid >> 4, dl = tid & 15;
        const int d = cg * 16 + dl;
        if (d < DD)
            out[(size_t)(rg * 64 + row) * DD + d] = h0r;
    }
}

extern "C" void kernel_launch(void* const* d_in, const int* in_sizes, int n_in,
                              void* d_out, int out_size, void* d_ws, size_t ws_size,
                              hipStream_t stream)
{
    const float* state = (const float*)d_in[0];
    const float* Wih   = (const float*)d_in[1];
    const float* Whh   = (const float*)d_in[2];
    const float* bih   = (const float*)d_in[3];
    const float* bhh   = (const float*)d_in[4];
    const float* bc    = (const float*)d_in[5];
    const int*   rec   = (const int*)d_in[6];

    char* ws = (char*)d_ws;
    float*    spart = (float*)ws;                   // 2 KB (8 shards x 64 t)
    unsigned* bar   = (unsigned*)(ws + 2048);       // 4 KB (32 groups + root)
    unsigned* garr  = (unsigned*)(ws + 6144);       // 1 KB (8 rg x 64B)
    f16*   ApB   = (f16*)(ws + 8192);               // 2 x 1 MB
    f16*   Wp0   = ApB + 2 * APCNT;                 // 6.29 MB
    f16*   Wp1   = Wp0 + WPCNT;                     // 6.29 MB
    float* hist  = (float*)(Wp1 + WPCNT);           // 8 MB (256x8x1024 f32)
    float* out   = (float*)d_out;

    hipMemsetAsync(ws, 0, 8192, stream);            // spart + bar + garr
    // rec==0 robustness: output = state if no iteration runs
    hipMemcpyAsync(out, state, (size_t)NELEM * sizeof(float),
                   hipMemcpyDeviceToDevice, stream);

    conv_w<<<dim3(NSTRIPS * WKSTEPS * 64 / 256), 256, 0, stream>>>(Wih, Whh, Wp0, Wp1);
    conv_a<<<dim3(MSTRIPS * AKSTEPS * 64 / 256), 256, 0, stream>>>(state, ApB);

    gru_persist<<<dim3(NBLK), dim3(1024), 0, stream>>>(
        ApB, Wp0, Wp1, bih, bhh, out, spart, bc, rec, bar, garr, hist);
}

// Round 16
// 1641.911 us; speedup vs baseline: 2.1802x; 2.1802x over previous
//
#include <hip/hip_runtime.h>
#include <math.h>
#include <stdint.h>

// Problem constants
#define DD 500
#define BB 512
// Permuted N layout: slab s (0..63) owns cols [32s, 32s+32) = [r|z|i_n|h_n]
// for d in [8s, 8s+8).  r/z cols hold x@(Wih+Whh) for t>=1 (x==h); t=0 uses
// Wp0 (Wih only in r/z).
// Split-precision: C = Ah·Wh + Al·Wh + Ah·Wl.  Wp k-order: [Wh|Wh|Wl]
// (wksteps 0..31 Wh(x Ah), 32..63 Wh(x Al), 64..95 Wl(x Ah)).
// Ap holds [Ah|Al] (64 ksteps, K=1024).
#define NSTRIPS 64     // n-strips (slabs) of 32
#define MSTRIPS 16     // m-strips of 32
#define WKSTEPS 96     // Wp ksteps of 16
#define AKSTEPS 64     // Ap ksteps of 16 ([Ah|Al])
#define NELEM (BB*DD)
// Persistent grid: 8 row-groups (64 rows) x 32 col-groups (2 slabs, 16 d)
// = 256 blocks x 1024 threads. 16 waves = slab x m-half x K-quarter:
// per-wave state fits the 4-wave/SIMD 128-VGPR cap (acc 16 + ring 32 +
// staging 16) -- R15's spill (VGPR=64, 2.3GB scratch fetch) is the
// counterexample this design removes. Per-wave MFMA chain: 24 ksteps.
#define GRG 8
#define GCG 32
#define NBLK 256
#define HSTRIDE 1024   // floats per (block, hist slot): 64 rows x 16 d

typedef _Float16 f16;
typedef _Float16 f16x8 __attribute__((ext_vector_type(8)));
typedef float    f32x16 __attribute__((ext_vector_type(16)));
typedef unsigned u32x4  __attribute__((ext_vector_type(4)));

#define APCNT ((size_t)MSTRIPS * AKSTEPS * 64 * 8)  // f16 per Ap buffer (1MB)
#define WPCNT ((size_t)NSTRIPS * WKSTEPS * 64 * 8)  // f16 per Wp buffer

// Fragment-order layout (Ap and Wp):
//   elem(strip, kstep, ln, j) at ((strip*KS + kstep)*64 + ln)*8 + j
//   row = strip*32 + (ln&31),  k = kstep*16 + (ln>>5)*8 + j
// = the mfma_f32_32x32x16_f16 A/B operand layout.

__device__ __forceinline__ float aload_f32(const float* p) {
    return __hip_atomic_load(p, __ATOMIC_RELAXED, __HIP_MEMORY_SCOPE_AGENT);
}
// Coalesced device-scope 16B load/store (sc0 sc1: served at the device
// coherence point). Used ONLY with an immediate vmcnt(0) drain.
__device__ __forceinline__ void aload16i(u32x4& d, const f16* p) {
    asm volatile("global_load_dwordx4 %0, %1, off sc0 sc1"
                 : "=&v"(d) : "v"(p) : "memory");
}
__device__ __forceinline__ void astore16(f16* p, u32x4 v) {
    asm volatile("global_store_dwordx4 %0, %1, off sc0 sc1"
                 :: "v"(p), "v"(v) : "memory");
}

// fast sigmoid/tanh via hardware v_exp: rel err ~1e-6
__device__ __forceinline__ float fsigmoid(float x) {
    return 1.0f / (1.0f + __expf(-x));
}
__device__ __forceinline__ float ftanh(float x) {
    return 2.0f / (1.0f + __expf(-2.0f * x)) - 1.0f;
}

// ---------------------------------------------------------------------------
// Wp0 (t=0) and Wp1 (t>=1), frag order, PERMUTED cols. k-blocks: [Wh|Wh|Wl].
// ---------------------------------------------------------------------------
__global__ __launch_bounds__(256) void conv_w(const float* __restrict__ Wih,
                                              const float* __restrict__ Whh,
                                              f16* __restrict__ Wp0,
                                              f16* __restrict__ Wp1)
{
    int p = blockIdx.x * 256 + threadIdx.x;    // (strip, kstep, ln)
    const int ln = p & 63; p >>= 6;
    const int kstep = p % WKSTEPS;
    const int strip = p / WKSTEPS;             // slab s, 0..63
    const int q = ln & 31;                     // col within slab
    const int g = q >> 3;                      // 0 r, 1 z, 2 i_n, 3 h_n
    const int d = strip * 8 + (q & 7);         // 0..511
    const int kb0 = kstep * 16 + (ln >> 5) * 8;
    const int blk = kb0 >> 9, bk0 = kb0 & 511;
    const float* pih = 0;
    const float* phh = 0;
    if (d < DD) {
        if (g == 0)      { pih = Wih + (size_t)d * DD;
                           phh = Whh + (size_t)d * DD; }
        else if (g == 1) { pih = Wih + (size_t)(500 + d) * DD;
                           phh = Whh + (size_t)(500 + d) * DD; }
        else if (g == 2) { pih = Wih + (size_t)(1000 + d) * DD; }
        else             { phh = Whh + (size_t)(1000 + d) * DD; }
    }
    f16 o0[8], o1[8];
    #pragma unroll
    for (int j = 0; j < 8; ++j) {
        const int bk = bk0 + j;
        float vi = 0.f, vh = 0.f;
        if (bk < DD) {
            if (pih) vi = pih[bk];
            if (phh) vh = phh[bk];
        }
        const float v0 = (g == 3) ? vh : vi;           // Wp0 value
        const float v1 = (g <= 1) ? (vi + vh) : v0;    // Wp1 value
        f16 h0 = (f16)v0;
        f16 h1 = (f16)v1;
        o0[j] = (blk == 2) ? (f16)(v0 - (float)h0) : h0;
        o1[j] = (blk == 2) ? (f16)(v1 - (float)h1) : h1;
    }
    const size_t off = ((size_t)(strip * WKSTEPS + kstep) * 64 + ln) * 8;
    *(uint4*)(Wp0 + off) = *(uint4*)o0;
    *(uint4*)(Wp1 + off) = *(uint4*)o1;
}

// ---------------------------------------------------------------------------
// Ap buffer 0 (frag order) from initial state. k-blocks: [Ah | Al], K=1024
// ---------------------------------------------------------------------------
__global__ __launch_bounds__(256) void conv_a(const float* __restrict__ S,
                                              f16* __restrict__ Ap)
{
    int p = blockIdx.x * 256 + threadIdx.x;    // (mstrip, kstep, ln)
    const int ln = p & 63; p >>= 6;
    const int kstep = p % AKSTEPS;
    const int strip = p / AKSTEPS;             // 0..15
    const int b = strip * 32 + (ln & 31);
    const int kb0 = kstep * 16 + (ln >> 5) * 8;
    const int blk = kb0 >> 9, bk0 = kb0 & 511;
    f16 out[8];
    #pragma unroll
    for (int j = 0; j < 8; ++j) {
        const int bk = bk0 + j;
        float v = (bk < DD) ? S[(size_t)b * DD + bk] : 0.f;
        f16 hi = (f16)v;
        out[j] = (blk == 1) ? (f16)(v - (float)hi) : hi;
    }
    *(uint4*)(Ap + ((size_t)(strip * AKSTEPS + kstep) * 64 + ln) * 8) = *(uint4*)out;
}

// ---------------------------------------------------------------------------
// Device-wide two-level barrier (once per 8-iter WINDOW only). Monotone,
// relaxed AGENT atomics. 32 groups of 8 blocks: bar[g*16] (64B apart),
// bar[512] root (32 arrivals), bar[528] generation.
// ---------------------------------------------------------------------------
__device__ __forceinline__ void grid_sync(unsigned* bar, unsigned e)
{
    __syncthreads();
    if (threadIdx.x == 0) {
        unsigned* gcnt = bar + ((blockIdx.x >> 3) << 4);
        unsigned* root = bar + 512;
        unsigned* gen  = bar + 528;
        unsigned a = __hip_atomic_fetch_add(gcnt, 1u, __ATOMIC_RELAXED,
                                            __HIP_MEMORY_SCOPE_AGENT);
        if (a == e * 8u + 7u) {
            unsigned r = __hip_atomic_fetch_add(root, 1u, __ATOMIC_RELAXED,
                                                __HIP_MEMORY_SCOPE_AGENT);
            if (r == e * 32u + 31u) {
                __hip_atomic_store(gen, e + 1u, __ATOMIC_RELAXED,
                                   __HIP_MEMORY_SCOPE_AGENT);
            } else {
                while (__hip_atomic_load(gen, __ATOMIC_RELAXED,
                                         __HIP_MEMORY_SCOPE_AGENT) <= e)
                    __builtin_amdgcn_s_sleep(1);
            }
        } else {
            while (__hip_atomic_load(gen, __ATOMIC_RELAXED,
                                     __HIP_MEMORY_SCOPE_AGENT) <= e)
                __builtin_amdgcn_s_sleep(1);
        }
    }
    __syncthreads();
}

// ---------------------------------------------------------------------------
// Persistent fused kernel, 256 blocks x 1024 threads, 16 waves =
// slab(2) x m-half(2) x K-quarter(4). Wave = ONE 32x32 tile, 24 wksteps
// (16 phase-H + 8 phase-L), single 8-slot B ring reused across phases.
// Per iter: prefill B | group wait | stage Ah + issue Al loads | phase-H
// MFMA | reload ring (Wh-L) | restage Al | phase-L MFMA | Ct combine
// (kq0 write, kq>0 LDS atomicAdd) | EW (1 elem/thr, h in reg) | pack |
// group signal. Grid sync + break scan every 8 iters (speculative, 8-deep
// h history ring). LDS 64KB time-multiplexed.
// ---------------------------------------------------------------------------
__global__ __launch_bounds__(1024, 4) void gru_persist(
    f16* __restrict__ ApB,                 // 2 buffers of APCNT
    const f16* __restrict__ Wp0, const f16* __restrict__ Wp1,
    const float* __restrict__ bih, const float* __restrict__ bhh,
    float* __restrict__ out, float* __restrict__ spart,  // [8][64] stride 64
    const float* __restrict__ bc, const int* __restrict__ rec,
    unsigned* __restrict__ bar, unsigned* __restrict__ garr,
    float* __restrict__ hist)
{
    const int bid = blockIdx.x;
    const int tid = threadIdx.x;
    const int rounds = min(64, rec[0]);
    if (rounds <= 0) return;               // uniform: no barriers entered
    const float thr = bc[0] * (float)NELEM;

    const int cg = bid & 31;               // col-group (d base = 16*cg)
    const int rg = bid >> 5;               // row-group (64 rows)
    const int wv = tid >> 6, ln = tid & 63;
    const int sl = wv & 1;                 // slab within pair
    const int mh = (wv >> 1) & 1;          // m-half (32 rows)
    const int kq = wv >> 2;                // K-quarter 0..3
    const int sb = cg * 2 + sl;            // this wave's global slab

    __shared__ __align__(16) char smem[65536];
    f16*      Alds  = (f16*)smem;                      // [2 strip][32 aks][64][8]
    float*    Ct    = (float*)smem;                    // [64][2 sl][4 g][9]
    unsigned* hbufP = (unsigned*)(smem + 20480);       // [64][17] hi|lo pack
    float*    red   = (float*)(smem + 24832);          // [16]
    int*      trig  = (int*)(smem + 24896);

    float h0r = 0.0f;                      // registered h state (1/thread)

    f16* bufs0 = ApB;
    f16* bufs1 = ApB + APCNT;
    unsigned* gptr = garr + rg * 16;       // group counter (own 64B line)
    unsigned wep = 0;                      // grid-sync episode

    for (int t = 0; t < rounds; ++t) {
        const f16* Wb    = (t == 0) ? Wp0 : Wp1;
        const f16* Abase = (t & 1) ? bufs1 : bufs0;
        f16*       Apw   = (t & 1) ? bufs0 : bufs1;    // EW writes other buf
        const f16* Bb    = Wb + (size_t)sb * WKSTEPS * 512 + (size_t)ln * 8;

        // phase-H B prefill: wk = kq*8 + i (Wh x Ah), i = 0..7
        uint4 rB[8];
        #pragma unroll
        for (int i = 0; i < 8; ++i)
            rB[i] = *(const uint4*)(Bb + (size_t)(kq * 8 + i) * 512);
        // group wait: all 32 producers of our A rows finished EW(t-1)
        if (t > 0) {
            if (tid == 0) {
                while (__hip_atomic_load(gptr, __ATOMIC_RELAXED,
                                         __HIP_MEMORY_SCOPE_AGENT)
                       < 32u * (unsigned)t)
                    __builtin_amdgcn_s_sleep(1);
            }
            __syncthreads();
        }

        // stage chunk H (Ah: aks 0..31, strips 2rg,2rg+1): 4 x 16B sc / thr
        u32x4 av[4];
        #pragma unroll
        for (int i = 0; i < 4; ++i) {
            const int flat = tid + 1024 * i;           // 16B units
            const int st_ = flat >> 11, rem = flat & 2047;
            aload16i(av[i], Abase +
                ((size_t)((2 * rg + st_) * AKSTEPS + (rem >> 6)) * 64
                 + (rem & 63)) * 8);
        }
        asm volatile("s_waitcnt vmcnt(0)" ::: "memory");
        __builtin_amdgcn_sched_barrier(0);
        #pragma unroll
        for (int i = 0; i < 4; ++i)
            *(u32x4*)(Alds + (size_t)(tid + 1024 * i) * 8) = av[i];
        // issue chunk L (Al: aks 32..63) loads NOW: latency hides under
        // phase-H MFMA (registers held across the phase)
        #pragma unroll
        for (int i = 0; i < 4; ++i) {
            const int flat = tid + 1024 * i;
            const int st_ = flat >> 11, rem = flat & 2047;
            aload16i(av[i], Abase +
                ((size_t)((2 * rg + st_) * AKSTEPS + 32 + (rem >> 6)) * 64
                 + (rem & 63)) * 8);
        }
        __syncthreads();

        // phase H: 16 ksteps (Ah x Wh then Ah x Wl). ka = kq*8 + (ksl&7);
        // ring slot ksl&7 is refilled with wk = 64+kq*8+ksl after first use.
        f32x16 acc = {};
        #pragma unroll
        for (int ksl = 0; ksl < 16; ++ksl) {
            const int ka = kq * 8 + (ksl & 7);
            f16x8 a = *(const f16x8*)(Alds + ((size_t)(mh * 32 + ka) * 512
                                              + (size_t)ln * 8));
            acc = __builtin_amdgcn_mfma_f32_32x32x16_f16(
                      a, *(f16x8*)&rB[ksl & 7], acc, 0, 0, 0);
            if (ksl < 8)                   // refill slot for Wl pass
                rB[ksl] = *(const uint4*)(Bb + (size_t)(64 + kq * 8 + ksl) * 512);
        }
        // reload ring for phase L: wk = 32 + kq*8 + i (Wh x Al)
        #pragma unroll
        for (int i = 0; i < 8; ++i)
            rB[i] = *(const uint4*)(Bb + (size_t)(32 + kq * 8 + i) * 512);
        __syncthreads();                   // phase-H A reads done

        // restage chunk L into the same buffer
        asm volatile("s_waitcnt vmcnt(0)" ::: "memory");
        __builtin_amdgcn_sched_barrier(0);
        #pragma unroll
        for (int i = 0; i < 4; ++i)
            *(u32x4*)(Alds + (size_t)(tid + 1024 * i) * 8) = av[i];
        __syncthreads();

        // phase L: 8 ksteps (Al x Wh). ka = kq*8 + ksl (local in chunk L).
        #pragma unroll
        for (int ksl = 0; ksl < 8; ++ksl) {
            const int ka = kq * 8 + ksl;
            f16x8 a = *(const f16x8*)(Alds + ((size_t)(mh * 32 + ka) * 512
                                              + (size_t)ln * 8));
            acc = __builtin_amdgcn_mfma_f32_32x32x16_f16(
                      a, *(f16x8*)&rB[ksl], acc, 0, 0, 0);
        }
        __syncthreads();                   // all MFMA done; A buffer dead

        // Ct combine, 2 rounds. C/D layout: col=lane&31,
        // row=mh*32+(r&3)+8*(r>>2)+4*(lane>>5). Ct = row*72 + sl*36 + g*9+dd
        {
            const int q = ln & 31, g = q >> 3, dd = q & 7;
            if (kq == 0) {
                #pragma unroll
                for (int r = 0; r < 16; ++r) {
                    const int row = mh * 32 + (r & 3) + 8 * (r >> 2)
                                    + 4 * (ln >> 5);
                    Ct[row * 72 + sl * 36 + g * 9 + dd] = acc[r];
                }
            }
            __syncthreads();
            if (kq != 0) {
                #pragma unroll
                for (int r = 0; r < 16; ++r) {
                    const int row = mh * 32 + (r & 3) + 8 * (r >> 2)
                                    + 4 * (ln >> 5);
                    atomicAdd(&Ct[row * 72 + sl * 36 + g * 9 + dd], acc[r]);
                }
            }
            __syncthreads();
        }

        // ---------------- EW phase (1 elem/thread, h in reg) --------------
        float* hw = hist + ((size_t)bid * 8 + (size_t)(t & 7)) * HSTRIDE;
        float psum = 0.0f;
        {
            const int row = tid >> 4, dl = tid & 15;
            const int d = cg * 16 + dl;
            const int sll = dl >> 3, dd = dl & 7;
            float hnew = 0.0f;
            if (d < DD) {
                const float* cb = &Ct[row * 72 + sll * 36 + dd];
                float cr = cb[0], cz = cb[9], cin = cb[18], chn = cb[27];
                float r = fsigmoid(cr + bih[d] + bhh[d]);
                float z = fsigmoid(cz + bih[500 + d] + bhh[500 + d]);
                float inn = cin + bih[1000 + d];
                float hn  = bhh[1000 + d];
                float hp  = 0.0f;
                if (t > 0) { hn += chn; hp = h0r; }
                float n = ftanh(inn + r * hn);
                hnew = (1.0f - z) * n + z * hp;
                psum = hnew;
            }
            h0r = hnew;
            hw[tid] = hnew;                    // history ring (block-private)
            f16 hi = (f16)hnew;
            f16 lo = (f16)(hnew - (float)hi);
            union { f16 f[2]; unsigned u; } pk;
            pk.f[0] = hi; pk.f[1] = lo;
            hbufP[row * 17 + dl] = pk.u;       // pad-striped
        }
        // block reduce psum -> spart shard (cg&7)
        #pragma unroll
        for (int off = 32; off > 0; off >>= 1) psum += __shfl_down(psum, off, 64);
        if (ln == 0) red[wv] = psum;
        __syncthreads();                        // red + hbufP ready
        if (tid == 0) {
            float v = 0.f;
            #pragma unroll
            for (int i = 0; i < 16; ++i) v += red[i];
            __hip_atomic_fetch_add(&spart[(size_t)(cg & 7) * 64 + t], v,
                                   __ATOMIC_RELAXED, __HIP_MEMORY_SCOPE_AGENT);
        }
        // pack Ap: (row 0..63, oct 0..1) -> d0 = cg*16 + oct*8.
        // hi kstep = cg, lo kstep = 32+cg, half = oct, strip = 2rg + row/32.
        if (tid < 128) {
            const int row = tid >> 1, oct = tid & 1;
            union { f16 a[8]; u32x4 v; } hiU, loU;
            #pragma unroll
            for (int j = 0; j < 8; ++j) {
                unsigned u = hbufP[row * 17 + oct * 8 + j];
                union { unsigned u; f16 f[2]; } pk; pk.u = u;
                hiU.a[j] = pk.f[0];
                loU.a[j] = pk.f[1];
            }
            const int strip = 2 * rg + (row >> 5), lm = row & 31;
            f16* dhi = Apw + ((size_t)(strip * AKSTEPS + cg)      * 64
                              + oct * 32 + lm) * 8;
            f16* dlo = Apw + ((size_t)(strip * AKSTEPS + 32 + cg) * 64
                              + oct * 32 + lm) * 8;
            astore16(dhi, hiU.v);
            astore16(dlo, loU.v);
        }
        asm volatile("s_waitcnt vmcnt(0)" ::: "memory");   // sc stores acked
        __syncthreads();
        if (tid == 0)
            __hip_atomic_fetch_add(gptr, 1u, __ATOMIC_RELAXED,
                                   __HIP_MEMORY_SCOPE_AGENT);

        // -------- window boundary: grid sync + break scan -----------------
        if (((t & 7) == 7) || (t == rounds - 1)) {
            grid_sync(bar, wep++);             // all spart(t' <= t) visible
            if (tid < 64) {                    // wave 0 scans the window
                const int cgl = tid & 7, ti = tid >> 3;
                const int tt = (t & ~7) + ti;
                float v = 0.f;
                if (tt <= t)
                    v = aload_f32(&spart[(size_t)cgl * 64 + tt]);
                v += __shfl_xor(v, 1, 64);
                v += __shfl_xor(v, 2, 64);
                v += __shfl_xor(v, 4, 64);
                bool hit = ((tid & 7) == 0) && (tt <= t) && (v > thr);
                unsigned long long m = __ballot(hit);
                if (tid == 0)
                    trig[0] = m ? (int)((__ffsll((long long)m) - 1) >> 3) : -1;
            }
            __syncthreads();
            const int w0 = trig[0];
            if (w0 >= 0) {                     // break fired at ts (uniform)
                const int ts = (t & ~7) + w0;
                const float* hs = hist
                    + ((size_t)bid * 8 + (size_t)(ts & 7)) * HSTRIDE;
                const int row = tid >> 4, dl = tid & 15;
                const int d = cg * 16 + dl;
                if (d < DD)
                    out[(size_t)(rg * 64 + row) * DD + d] = hs[tid];
                return;
            }
        }
    }

    // no trigger: final output from registered h
    {
        const int row = tid >> 4, dl = tid & 15;
        const int d = cg * 16 + dl;
        if (d < DD)
            out[(size_t)(rg * 64 + row) * DD + d] = h0r;
    }
}

extern "C" void kernel_launch(void* const* d_in, const int* in_sizes, int n_in,
                              void* d_out, int out_size, void* d_ws, size_t ws_size,
                              hipStream_t stream)
{
    const float* state = (const float*)d_in[0];
    const float* Wih   = (const float*)d_in[1];
    const float* Whh   = (const float*)d_in[2];
    const float* bih   = (const float*)d_in[3];
    const float* bhh   = (const float*)d_in[4];
    const float* bc    = (const float*)d_in[5];
    const int*   rec   = (const int*)d_in[6];

    char* ws = (char*)d_ws;
    float*    spart = (float*)ws;                   // 2 KB (8 shards x 64 t)
    unsigned* bar   = (unsigned*)(ws + 2048);       // 4 KB (32 groups + root)
    unsigned* garr  = (unsigned*)(ws + 6144);       // 1 KB (8 rg x 64B)
    f16*   ApB   = (f16*)(ws + 8192);               // 2 x 1 MB
    f16*   Wp0   = ApB + 2 * APCNT;                 // 6.29 MB
    f16*   Wp1   = Wp0 + WPCNT;                     // 6.29 MB
    float* hist  = (float*)(Wp1 + WPCNT);           // 8 MB (256x8x1024 f32)
    float* out   = (float*)d_out;

    hipMemsetAsync(ws, 0, 8192, stream);            // spart + bar + garr
    // rec==0 robustness: output = state if no iteration runs
    hipMemcpyAsync(out, state, (size_t)NELEM * sizeof(float),
                   hipMemcpyDeviceToDevice, stream);

    conv_w<<<dim3(NSTRIPS * WKSTEPS * 64 / 256), 256, 0, stream>>>(Wih, Whh, Wp0, Wp1);
    conv_a<<<dim3(MSTRIPS * AKSTEPS * 64 / 256), 256, 0, stream>>>(state, ApB);

    gru_persist<<<dim3(NBLK), dim3(1024), 0, stream>>>(
        ApB, Wp0, Wp1, bih, bhh, out, spart, bc, rec, bar, garr, hist);
}

// Round 17
// 1596.249 us; speedup vs baseline: 2.2425x; 1.0286x over previous
//
#include <hip/hip_runtime.h>
#include <math.h>
#include <stdint.h>

// Problem constants
#define DD 500
#define BB 512
// Permuted N layout: slab s (0..63) owns cols [32s, 32s+32) = [r|z|i_n|h_n]
// for d in [8s, 8s+8).  r/z cols hold x@(Wih+Whh) for t>=1 (x==h); t=0 uses
// Wp0 (Wih only in r/z).
// Split-precision: C = Ah·Wh + Al·Wh + Ah·Wl.  Wp k-order: [Wh|Wh|Wl]
// (wksteps 0..31 Wh(x Ah), 32..63 Wh(x Al), 64..95 Wl(x Ah)).
// Ap holds [Ah|Al] (64 ksteps, K=1024).
#define NSTRIPS 64     // n-strips (slabs) of 32
#define MSTRIPS 16     // m-strips of 32
#define WKSTEPS 96     // Wp ksteps of 16
#define AKSTEPS 64     // Ap ksteps of 16 ([Ah|Al])
#define NELEM (BB*DD)
// Persistent grid: 8 row-groups (64 rows) x 32 col-groups (2 slabs, 16 d)
// = 256 blocks x 512 threads = ALL 256 CUs (R14 measured-best config:
// 8 waves = m-half x K-quarter, 2 accs/wave, VGPR 124). bid%8 = cg%8 ->
// blocks sharing a B slice land on one XCD.
#define GRG 8
#define GCG 32
#define NBLK 256
#define HSTRIDE 1024   // floats per (block, hist slot): 64 rows x 16 d

typedef _Float16 f16;
typedef _Float16 f16x8 __attribute__((ext_vector_type(8)));
typedef float    f32x16 __attribute__((ext_vector_type(16)));
typedef unsigned u32x4  __attribute__((ext_vector_type(4)));

#define APCNT ((size_t)MSTRIPS * AKSTEPS * 64 * 8)  // f16 per Ap buffer (1MB)
#define WPCNT ((size_t)NSTRIPS * WKSTEPS * 64 * 8)  // f16 per Wp buffer

// Fragment-order layout (Ap and Wp):
//   elem(strip, kstep, ln, j) at ((strip*KS + kstep)*64 + ln)*8 + j
//   row = strip*32 + (ln&31),  k = kstep*16 + (ln>>5)*8 + j
// = the mfma_f32_32x32x16_f16 A/B operand layout.

__device__ __forceinline__ float aload_f32(const float* p) {
    return __hip_atomic_load(p, __ATOMIC_RELAXED, __HIP_MEMORY_SCOPE_AGENT);
}
// Coalesced device-scope 16B load/store (sc0 sc1: served at the device
// coherence point). Used ONLY with an immediate vmcnt(0) drain.
__device__ __forceinline__ void aload16i(u32x4& d, const f16* p) {
    asm volatile("global_load_dwordx4 %0, %1, off sc0 sc1"
                 : "=&v"(d) : "v"(p) : "memory");
}
__device__ __forceinline__ void astore16(f16* p, u32x4 v) {
    asm volatile("global_store_dwordx4 %0, %1, off sc0 sc1"
                 :: "v"(p), "v"(v) : "memory");
}

// fast sigmoid/tanh via hardware v_exp: rel err ~1e-6
__device__ __forceinline__ float fsigmoid(float x) {
    return 1.0f / (1.0f + __expf(-x));
}
__device__ __forceinline__ float ftanh(float x) {
    return 2.0f / (1.0f + __expf(-2.0f * x)) - 1.0f;
}

// ---------------------------------------------------------------------------
// Wp0 (t=0) and Wp1 (t>=1), frag order, PERMUTED cols. k-blocks: [Wh|Wh|Wl].
// ---------------------------------------------------------------------------
__global__ __launch_bounds__(256) void conv_w(const float* __restrict__ Wih,
                                              const float* __restrict__ Whh,
                                              f16* __restrict__ Wp0,
                                              f16* __restrict__ Wp1)
{
    int p = blockIdx.x * 256 + threadIdx.x;    // (strip, kstep, ln)
    const int ln = p & 63; p >>= 6;
    const int kstep = p % WKSTEPS;
    const int strip = p / WKSTEPS;             // slab s, 0..63
    const int q = ln & 31;                     // col within slab
    const int g = q >> 3;                      // 0 r, 1 z, 2 i_n, 3 h_n
    const int d = strip * 8 + (q & 7);         // 0..511
    const int kb0 = kstep * 16 + (ln >> 5) * 8;
    const int blk = kb0 >> 9, bk0 = kb0 & 511;
    const float* pih = 0;
    const float* phh = 0;
    if (d < DD) {
        if (g == 0)      { pih = Wih + (size_t)d * DD;
                           phh = Whh + (size_t)d * DD; }
        else if (g == 1) { pih = Wih + (size_t)(500 + d) * DD;
                           phh = Whh + (size_t)(500 + d) * DD; }
        else if (g == 2) { pih = Wih + (size_t)(1000 + d) * DD; }
        else             { phh = Whh + (size_t)(1000 + d) * DD; }
    }
    f16 o0[8], o1[8];
    #pragma unroll
    for (int j = 0; j < 8; ++j) {
        const int bk = bk0 + j;
        float vi = 0.f, vh = 0.f;
        if (bk < DD) {
            if (pih) vi = pih[bk];
            if (phh) vh = phh[bk];
        }
        const float v0 = (g == 3) ? vh : vi;           // Wp0 value
        const float v1 = (g <= 1) ? (vi + vh) : v0;    // Wp1 value
        f16 h0 = (f16)v0;
        f16 h1 = (f16)v1;
        o0[j] = (blk == 2) ? (f16)(v0 - (float)h0) : h0;
        o1[j] = (blk == 2) ? (f16)(v1 - (float)h1) : h1;
    }
    const size_t off = ((size_t)(strip * WKSTEPS + kstep) * 64 + ln) * 8;
    *(uint4*)(Wp0 + off) = *(uint4*)o0;
    *(uint4*)(Wp1 + off) = *(uint4*)o1;
}

// ---------------------------------------------------------------------------
// Ap buffer 0 (frag order) from initial state. k-blocks: [Ah | Al], K=1024
// ---------------------------------------------------------------------------
__global__ __launch_bounds__(256) void conv_a(const float* __restrict__ S,
                                              f16* __restrict__ Ap)
{
    int p = blockIdx.x * 256 + threadIdx.x;    // (mstrip, kstep, ln)
    const int ln = p & 63; p >>= 6;
    const int kstep = p % AKSTEPS;
    const int strip = p / AKSTEPS;             // 0..15
    const int b = strip * 32 + (ln & 31);
    const int kb0 = kstep * 16 + (ln >> 5) * 8;
    const int blk = kb0 >> 9, bk0 = kb0 & 511;
    f16 out[8];
    #pragma unroll
    for (int j = 0; j < 8; ++j) {
        const int bk = bk0 + j;
        float v = (bk < DD) ? S[(size_t)b * DD + bk] : 0.f;
        f16 hi = (f16)v;
        out[j] = (blk == 1) ? (f16)(v - (float)hi) : hi;
    }
    *(uint4*)(Ap + ((size_t)(strip * AKSTEPS + kstep) * 64 + ln) * 8) = *(uint4*)out;
}

// ---------------------------------------------------------------------------
// Device-wide two-level barrier (once per 8-iter WINDOW only). Monotone,
// relaxed AGENT atomics. 32 groups of 8 blocks: bar[g*16] (64B apart),
// bar[512] root (32 arrivals), bar[528] generation.
// ---------------------------------------------------------------------------
__device__ __forceinline__ void grid_sync(unsigned* bar, unsigned e)
{
    __syncthreads();
    if (threadIdx.x == 0) {
        unsigned* gcnt = bar + ((blockIdx.x >> 3) << 4);
        unsigned* root = bar + 512;
        unsigned* gen  = bar + 528;
        unsigned a = __hip_atomic_fetch_add(gcnt, 1u, __ATOMIC_RELAXED,
                                            __HIP_MEMORY_SCOPE_AGENT);
        if (a == e * 8u + 7u) {
            unsigned r = __hip_atomic_fetch_add(root, 1u, __ATOMIC_RELAXED,
                                                __HIP_MEMORY_SCOPE_AGENT);
            if (r == e * 32u + 31u) {
                __hip_atomic_store(gen, e + 1u, __ATOMIC_RELAXED,
                                   __HIP_MEMORY_SCOPE_AGENT);
            } else {
                while (__hip_atomic_load(gen, __ATOMIC_RELAXED,
                                         __HIP_MEMORY_SCOPE_AGENT) <= e)
                    __builtin_amdgcn_s_sleep(1);
            }
        } else {
            while (__hip_atomic_load(gen, __ATOMIC_RELAXED,
                                     __HIP_MEMORY_SCOPE_AGENT) <= e)
                __builtin_amdgcn_s_sleep(1);
        }
    }
    __syncthreads();
}

// ---------------------------------------------------------------------------
// Persistent fused kernel, 256 blocks x 512 threads (8 waves = m-half x
// K-quarter). Block = 64 rows x 2 slabs x full K.  (R14 measured-best
// structure; only change: Ct combine is 2 rounds via LDS atomicAdd --
// validated correct on HW in R16 -- instead of 4 serialized rounds.)
// ---------------------------------------------------------------------------
__global__ __launch_bounds__(512, 2) void gru_persist(
    f16* __restrict__ ApB,                 // 2 buffers of APCNT
    const f16* __restrict__ Wp0, const f16* __restrict__ Wp1,
    const float* __restrict__ bih, const float* __restrict__ bhh,
    float* __restrict__ out, float* __restrict__ spart,  // [8][64] stride 64
    const float* __restrict__ bc, const int* __restrict__ rec,
    unsigned* __restrict__ bar, unsigned* __restrict__ garr,
    float* __restrict__ hist)
{
    const int bid = blockIdx.x;
    const int tid = threadIdx.x;
    const int rounds = min(64, rec[0]);
    if (rounds <= 0) return;               // uniform: no barriers entered
    const float thr = bc[0] * (float)NELEM;

    const int cg = bid & 31;               // col-group (d base = 16*cg)
    const int rg = bid >> 5;               // row-group (64 rows)
    const int wv = tid >> 6, ln = tid & 63;
    const int mh = wv >> 2;                // m-half (32 rows)
    const int kq = wv & 3;                 // K-quarter
    const int sb0 = cg * 2, sb1 = cg * 2 + 1;          // this block's slabs

    __shared__ __align__(16) char smem[65536];
    f16*      Alds  = (f16*)smem;                      // [2 sl][32 aks][64][8]
    float*    Ct    = (float*)smem;                    // [64][2 sl][4 g][9]
    unsigned* hbufP = (unsigned*)(smem + 20480);       // [64][17] hi|lo pack
    float*    red   = (float*)(smem + 24832);          // [8]
    int*      trig  = (int*)(smem + 24864);

    float h[2];                            // registered h state (own slots)
    h[0] = 0.0f; h[1] = 0.0f;

    f16* bufs0 = ApB;
    f16* bufs1 = ApB + APCNT;
    unsigned* gptr = garr + rg * 16;       // group counter (own 64B line)
    unsigned wep = 0;                      // grid-sync episode

    for (int t = 0; t < rounds; ++t) {
        const f16* Wb    = (t == 0) ? Wp0 : Wp1;
        const f16* Abase = (t & 1) ? bufs1 : bufs0;
        f16*       Apw   = (t & 1) ? bufs0 : bufs1;    // EW writes other buf
        const f16* Bb0   = Wb + (size_t)sb0 * WKSTEPS * 512 + (size_t)ln * 8;
        const f16* Bb1   = Wb + (size_t)sb1 * WKSTEPS * 512 + (size_t)ln * 8;

        // phase-H B ring prefill: wk = kq*8 + i (independent of Ap)
        uint4 rB0[8], rB1[8];
        #pragma unroll
        for (int i = 0; i < 8; ++i) {
            rB0[i] = *(const uint4*)(Bb0 + (size_t)(kq * 8 + i) * 512);
            rB1[i] = *(const uint4*)(Bb1 + (size_t)(kq * 8 + i) * 512);
        }
        // group wait: all 32 producers of our A rows finished EW(t-1)
        if (t > 0) {
            if (tid == 0) {
                while (__hip_atomic_load(gptr, __ATOMIC_RELAXED,
                                         __HIP_MEMORY_SCOPE_AGENT)
                       < 32u * (unsigned)t)
                    __builtin_amdgcn_s_sleep(1);
            }
            __syncthreads();
        }

        // stage chunk H (Ah: aks 0..31, strips 2rg,2rg+1): 8 x 16B sc / thr
        u32x4 av[8];
        #pragma unroll
        for (int i = 0; i < 8; ++i) {
            const int flat = tid + 512 * i;
            const int sl_ = flat >> 11, rem = flat & 2047;
            aload16i(av[i], Abase +
                ((size_t)((2 * rg + sl_) * AKSTEPS + (rem >> 6)) * 64
                 + (rem & 63)) * 8);
        }
        asm volatile("s_waitcnt vmcnt(0)" ::: "memory");
        __builtin_amdgcn_sched_barrier(0);
        #pragma unroll
        for (int i = 0; i < 8; ++i)
            *(u32x4*)(Alds + (size_t)(tid + 512 * i) * 8) = av[i];
        // issue chunk L (Al: aks 32..63) loads NOW: latency hides under
        // phase-H MFMA (registers held across the phase)
        #pragma unroll
        for (int i = 0; i < 8; ++i) {
            const int flat = tid + 512 * i;
            const int sl_ = flat >> 11, rem = flat & 2047;
            aload16i(av[i], Abase +
                ((size_t)((2 * rg + sl_) * AKSTEPS + 32 + (rem >> 6)) * 64
                 + (rem & 63)) * 8);
        }
        __syncthreads();

        // phase H: 16 ksteps/wave. wk = kq*8+ksl (ksl<8) or 64+kq*8+(ksl-8);
        // A kstep ka = kq*8 + (ksl&7) in both (Ah pairs with Wh and Wl).
        f32x16 acc0 = {}, acc1 = {};
        #pragma unroll
        for (int ksl = 0; ksl < 16; ++ksl) {
            const int ka = kq * 8 + (ksl & 7);
            f16x8 a = *(const f16x8*)(Alds + ((size_t)(mh * 32 + ka) * 512
                                              + (size_t)ln * 8));
            acc0 = __builtin_amdgcn_mfma_f32_32x32x16_f16(
                       a, *(f16x8*)&rB0[ksl & 7], acc0, 0, 0, 0);
            acc1 = __builtin_amdgcn_mfma_f32_32x32x16_f16(
                       a, *(f16x8*)&rB1[ksl & 7], acc1, 0, 0, 0);
            if (ksl < 8) {                 // refill slot ksl with wk=64+kq*8+ksl
                rB0[ksl] = *(const uint4*)(Bb0 + (size_t)(64 + kq * 8 + ksl) * 512);
                rB1[ksl] = *(const uint4*)(Bb1 + (size_t)(64 + kq * 8 + ksl) * 512);
            }
        }
        __syncthreads();                   // phase-H A reads done

        // restage chunk L into the same buffer
        asm volatile("s_waitcnt vmcnt(0)" ::: "memory");
        __builtin_amdgcn_sched_barrier(0);
        #pragma unroll
        for (int i = 0; i < 8; ++i)
            *(u32x4*)(Alds + (size_t)(tid + 512 * i) * 8) = av[i];
        // phase-L B ring prefill: wk = 32 + kq*8 + i
        #pragma unroll
        for (int i = 0; i < 8; ++i) {
            rB0[i] = *(const uint4*)(Bb0 + (size_t)(32 + kq * 8 + i) * 512);
            rB1[i] = *(const uint4*)(Bb1 + (size_t)(32 + kq * 8 + i) * 512);
        }
        __syncthreads();

        // phase L: 8 ksteps/wave (Al x Wh)
        #pragma unroll
        for (int ksl = 0; ksl < 8; ++ksl) {
            const int ka = kq * 8 + ksl;
            f16x8 a = *(const f16x8*)(Alds + ((size_t)(mh * 32 + ka) * 512
                                              + (size_t)ln * 8));
            acc0 = __builtin_amdgcn_mfma_f32_32x32x16_f16(
                       a, *(f16x8*)&rB0[ksl], acc0, 0, 0, 0);
            acc1 = __builtin_amdgcn_mfma_f32_32x32x16_f16(
                       a, *(f16x8*)&rB1[ksl], acc1, 0, 0, 0);
        }
        __syncthreads();                   // all MFMA done; A buffer dead

        // Ct combine, 2 rounds (R16-validated LDS atomicAdd). C/D layout:
        // col=lane&31, row=(r&3)+8*(r>>2)+4*(lane>>5).
        // Ct addr = row*72 + sl*36 + g*9 + dd
        {
            const int q = ln & 31, g = q >> 3, dd = q & 7;
            if (kq == 0) {
                #pragma unroll
                for (int r = 0; r < 16; ++r) {
                    const int row = mh * 32 + (r & 3) + 8 * (r >> 2)
                                    + 4 * (ln >> 5);
                    float* c0 = Ct + row * 72 + g * 9 + dd;
                    c0[0]  = acc0[r];
                    c0[36] = acc1[r];
                }
            }
            __syncthreads();
            if (kq != 0) {
                #pragma unroll
                for (int r = 0; r < 16; ++r) {
                    const int row = mh * 32 + (r & 3) + 8 * (r >> 2)
                                    + 4 * (ln >> 5);
                    float* c0 = Ct + row * 72 + g * 9 + dd;
                    atomicAdd(c0,      acc0[r]);
                    atomicAdd(c0 + 36, acc1[r]);
                }
            }
            __syncthreads();
        }

        // ---------------- EW phase (h in registers) -----------------------
        float* hw = hist + ((size_t)bid * 8 + (size_t)(t & 7)) * HSTRIDE;
        float psum = 0.0f;
        #pragma unroll
        for (int i = 0; i < 2; ++i) {
            const int idx = i * 512 + tid;     // 1024 (row, dl) pairs
            const int row = idx >> 4, dl = idx & 15;
            const int d = cg * 16 + dl;
            const int sl = dl >> 3, dd = dl & 7;
            float hnew = 0.0f;
            if (d < DD) {
                const float* cb = &Ct[row * 72 + sl * 36 + dd];
                float cr = cb[0], cz = cb[9], cin = cb[18], chn = cb[27];
                float r = fsigmoid(cr + bih[d] + bhh[d]);
                float z = fsigmoid(cz + bih[500 + d] + bhh[500 + d]);
                float inn = cin + bih[1000 + d];
                float hn  = bhh[1000 + d];
                float hp  = 0.0f;
                if (t > 0) { hn += chn; hp = h[i]; }
                float n = ftanh(inn + r * hn);
                hnew = (1.0f - z) * n + z * hp;
                psum += hnew;
            }
            h[i] = hnew;
            hw[idx] = hnew;                    // history ring (block-private)
            f16 hi = (f16)hnew;
            f16 lo = (f16)(hnew - (float)hi);
            union { f16 f[2]; unsigned u; } pk;
            pk.f[0] = hi; pk.f[1] = lo;
            hbufP[row * 17 + dl] = pk.u;       // pad-striped
        }
        // block reduce psum -> spart shard (cg&7)
        #pragma unroll
        for (int off = 32; off > 0; off >>= 1) psum += __shfl_down(psum, off, 64);
        if (ln == 0) red[wv] = psum;
        __syncthreads();                        // red + hbufP ready
        if (tid == 0) {
            float v = red[0] + red[1] + red[2] + red[3]
                    + red[4] + red[5] + red[6] + red[7];
            __hip_atomic_fetch_add(&spart[(size_t)(cg & 7) * 64 + t], v,
                                   __ATOMIC_RELAXED, __HIP_MEMORY_SCOPE_AGENT);
        }
        // pack Ap: (row 0..63, oct 0..1) -> d0 = cg*16 + oct*8.
        // hi kstep = cg, lo kstep = 32+cg, half = oct, strip = 2rg + row/32.
        if (tid < 128) {
            const int row = tid >> 1, oct = tid & 1;
            union { f16 a[8]; u32x4 v; } hiU, loU;
            #pragma unroll
            for (int j = 0; j < 8; ++j) {
                unsigned u = hbufP[row * 17 + oct * 8 + j];
                union { unsigned u; f16 f[2]; } pk; pk.u = u;
                hiU.a[j] = pk.f[0];
                loU.a[j] = pk.f[1];
            }
            const int strip = 2 * rg + (row >> 5), lm = row & 31;
            f16* dhi = Apw + ((size_t)(strip * AKSTEPS + cg)      * 64
                              + oct * 32 + lm) * 8;
            f16* dlo = Apw + ((size_t)(strip * AKSTEPS + 32 + cg) * 64
                              + oct * 32 + lm) * 8;
            astore16(dhi, hiU.v);
            astore16(dlo, loU.v);
        }
        asm volatile("s_waitcnt vmcnt(0)" ::: "memory");   // sc stores acked
        __syncthreads();
        if (tid == 0)
            __hip_atomic_fetch_add(gptr, 1u, __ATOMIC_RELAXED,
                                   __HIP_MEMORY_SCOPE_AGENT);

        // -------- window boundary: grid sync + break scan -----------------
        if (((t & 7) == 7) || (t == rounds - 1)) {
            grid_sync(bar, wep++);             // all spart(t' <= t) visible
            if (tid < 64) {                    // wave 0 scans the window
                const int cgl = tid & 7, ti = tid >> 3;
                const int tt = (t & ~7) + ti;
                float v = 0.f;
                if (tt <= t)
                    v = aload_f32(&spart[(size_t)cgl * 64 + tt]);
                v += __shfl_xor(v, 1, 64);
                v += __shfl_xor(v, 2, 64);
                v += __shfl_xor(v, 4, 64);
                bool hit = ((tid & 7) == 0) && (tt <= t) && (v > thr);
                unsigned long long m = __ballot(hit);
                if (tid == 0)
                    trig[0] = m ? (int)((__ffsll((long long)m) - 1) >> 3) : -1;
            }
            __syncthreads();
            const int w0 = trig[0];
            if (w0 >= 0) {                     // break fired at ts (uniform)
                const int ts = (t & ~7) + w0;
                const float* hs = hist
                    + ((size_t)bid * 8 + (size_t)(ts & 7)) * HSTRIDE;
                #pragma unroll
                for (int i = 0; i < 2; ++i) {
                    const int idx = i * 512 + tid;
                    const int row = idx >> 4, dl = idx & 15;
                    const int d = cg * 16 + dl;
                    if (d < DD)
                        out[(size_t)(rg * 64 + row) * DD + d] = hs[idx];
                }
                return;
            }
        }
    }

    // no trigger: final output from registered h
    #pragma unroll
    for (int i = 0; i < 2; ++i) {
        const int idx = i * 512 + tid;
        const int row = idx >> 4, dl = idx & 15;
        const int d = cg * 16 + dl;
        if (d < DD)
            out[(size_t)(rg * 64 + row) * DD + d] = h[i];
    }
}

extern "C" void kernel_launch(void* const* d_in, const int* in_sizes, int n_in,
                              void* d_out, int out_size, void* d_ws, size_t ws_size,
                              hipStream_t stream)
{
    const float* state = (const float*)d_in[0];
    const float* Wih   = (const float*)d_in[1];
    const float* Whh   = (const float*)d_in[2];
    const float* bih   = (const float*)d_in[3];
    const float* bhh   = (const float*)d_in[4];
    const float* bc    = (const float*)d_in[5];
    const int*   rec   = (const int*)d_in[6];

    char* ws = (char*)d_ws;
    float*    spart = (float*)ws;                   // 2 KB (8 shards x 64 t)
    unsigned* bar   = (unsigned*)(ws + 2048);       // 4 KB (32 groups + root)
    unsigned* garr  = (unsigned*)(ws + 6144);       // 1 KB (8 rg x 64B)
    f16*   ApB   = (f16*)(ws + 8192);               // 2 x 1 MB
    f16*   Wp0   = ApB + 2 * APCNT;                 // 6.29 MB
    f16*   Wp1   = Wp0 + WPCNT;                     // 6.29 MB
    float* hist  = (float*)(Wp1 + WPCNT);           // 8 MB (256x8x1024 f32)
    float* out   = (float*)d_out;

    hipMemsetAsync(ws, 0, 8192, stream);            // spart + bar + garr
    // rec==0 robustness: output = state if no iteration runs
    hipMemcpyAsync(out, state, (size_t)NELEM * sizeof(float),
                   hipMemcpyDeviceToDevice, stream);

    conv_w<<<dim3(NSTRIPS * WKSTEPS * 64 / 256), 256, 0, stream>>>(Wih, Whh, Wp0, Wp1);
    conv_a<<<dim3(MSTRIPS * AKSTEPS * 64 / 256), 256, 0, stream>>>(state, ApB);

    gru_persist<<<dim3(NBLK), dim3(512), 0, stream>>>(
        ApB, Wp0, Wp1, bih, bhh, out, spart, bc, rec, bar, garr, hist);
}

// Round 18
// 692.208 us; speedup vs baseline: 5.1713x; 2.3060x over previous
//
#include <hip/hip_runtime.h>
#include <math.h>
#include <stdint.h>

// Problem constants
#define DD 500
#define BB 512
// Permuted N layout: slab s (0..63) owns cols [32s, 32s+32) = [r|z|i_n|h_n]
// for d in [8s, 8s+8).  r/z cols hold x@(Wih+Whh) for t>=1 (x==h); t=0 uses
// Wp0 (Wih only in r/z).
// Split-precision: C = Ah·Wh + Al·Wh + Ah·Wl.  Wp k-order: [Wh|Wh|Wl]
// (wksteps 0..31 Wh(x Ah), 32..63 Wh(x Al), 64..95 Wl(x Ah)).
// Ap holds [Ah|Al] (64 ksteps, K=1024).
#define NSTRIPS 64     // n-strips (slabs) of 32
#define MSTRIPS 16     // m-strips of 32
#define WKSTEPS 96     // Wp ksteps of 16
#define AKSTEPS 64     // Ap ksteps of 16 ([Ah|Al])
#define NELEM (BB*DD)
// Persistent grid: 8 row-groups (64 rows) x 32 col-groups (2 slabs, 16 d)
// = 256 blocks x 512 threads = ALL 256 CUs. bid%8 = cg%8 -> blocks sharing a
// B slice land on one XCD (786KB Wp slice per XCD L2).
// B volume/iter: (512/64) x 6.3MB = 50MB. Per-wave chain: 24 ksteps
// (8 waves = m-half x K-quarter).  [R14 measured-best: 650us kernel]
#define GRG 8
#define GCG 32
#define NBLK 256
#define HSTRIDE 1024   // floats per (block, hist slot): 64 rows x 16 d

typedef _Float16 f16;
typedef _Float16 f16x8 __attribute__((ext_vector_type(8)));
typedef float    f32x16 __attribute__((ext_vector_type(16)));
typedef unsigned u32x4  __attribute__((ext_vector_type(4)));

#define APCNT ((size_t)MSTRIPS * AKSTEPS * 64 * 8)  // f16 per Ap buffer (1MB)
#define WPCNT ((size_t)NSTRIPS * WKSTEPS * 64 * 8)  // f16 per Wp buffer

// Fragment-order layout (Ap and Wp):
//   elem(strip, kstep, ln, j) at ((strip*KS + kstep)*64 + ln)*8 + j
//   row = strip*32 + (ln&31),  k = kstep*16 + (ln>>5)*8 + j
// = the mfma_f32_32x32x16_f16 A/B operand layout.

__device__ __forceinline__ float aload_f32(const float* p) {
    return __hip_atomic_load(p, __ATOMIC_RELAXED, __HIP_MEMORY_SCOPE_AGENT);
}
// Coalesced device-scope 16B load/store (sc0 sc1: served at the device
// coherence point). Used ONLY with an immediate vmcnt(0) drain.
__device__ __forceinline__ void aload16i(u32x4& d, const f16* p) {
    asm volatile("global_load_dwordx4 %0, %1, off sc0 sc1"
                 : "=&v"(d) : "v"(p) : "memory");
}
__device__ __forceinline__ void astore16(f16* p, u32x4 v) {
    asm volatile("global_store_dwordx4 %0, %1, off sc0 sc1"
                 :: "v"(p), "v"(v) : "memory");
}

// fast sigmoid/tanh via hardware v_exp: rel err ~1e-6
__device__ __forceinline__ float fsigmoid(float x) {
    return 1.0f / (1.0f + __expf(-x));
}
__device__ __forceinline__ float ftanh(float x) {
    return 2.0f / (1.0f + __expf(-2.0f * x)) - 1.0f;
}

// ---------------------------------------------------------------------------
// Wp0 (t=0) and Wp1 (t>=1), frag order, PERMUTED cols. k-blocks: [Wh|Wh|Wl].
// ---------------------------------------------------------------------------
__global__ __launch_bounds__(256) void conv_w(const float* __restrict__ Wih,
                                              const float* __restrict__ Whh,
                                              f16* __restrict__ Wp0,
                                              f16* __restrict__ Wp1)
{
    int p = blockIdx.x * 256 + threadIdx.x;    // (strip, kstep, ln)
    const int ln = p & 63; p >>= 6;
    const int kstep = p % WKSTEPS;
    const int strip = p / WKSTEPS;             // slab s, 0..63
    const int q = ln & 31;                     // col within slab
    const int g = q >> 3;                      // 0 r, 1 z, 2 i_n, 3 h_n
    const int d = strip * 8 + (q & 7);         // 0..511
    const int kb0 = kstep * 16 + (ln >> 5) * 8;
    const int blk = kb0 >> 9, bk0 = kb0 & 511;
    const float* pih = 0;
    const float* phh = 0;
    if (d < DD) {
        if (g == 0)      { pih = Wih + (size_t)d * DD;
                           phh = Whh + (size_t)d * DD; }
        else if (g == 1) { pih = Wih + (size_t)(500 + d) * DD;
                           phh = Whh + (size_t)(500 + d) * DD; }
        else if (g == 2) { pih = Wih + (size_t)(1000 + d) * DD; }
        else             { phh = Whh + (size_t)(1000 + d) * DD; }
    }
    f16 o0[8], o1[8];
    #pragma unroll
    for (int j = 0; j < 8; ++j) {
        const int bk = bk0 + j;
        float vi = 0.f, vh = 0.f;
        if (bk < DD) {
            if (pih) vi = pih[bk];
            if (phh) vh = phh[bk];
        }
        const float v0 = (g == 3) ? vh : vi;           // Wp0 value
        const float v1 = (g <= 1) ? (vi + vh) : v0;    // Wp1 value
        f16 h0 = (f16)v0;
        f16 h1 = (f16)v1;
        o0[j] = (blk == 2) ? (f16)(v0 - (float)h0) : h0;
        o1[j] = (blk == 2) ? (f16)(v1 - (float)h1) : h1;
    }
    const size_t off = ((size_t)(strip * WKSTEPS + kstep) * 64 + ln) * 8;
    *(uint4*)(Wp0 + off) = *(uint4*)o0;
    *(uint4*)(Wp1 + off) = *(uint4*)o1;
}

// ---------------------------------------------------------------------------
// Ap buffer 0 (frag order) from initial state. k-blocks: [Ah | Al], K=1024
// ---------------------------------------------------------------------------
__global__ __launch_bounds__(256) void conv_a(const float* __restrict__ S,
                                              f16* __restrict__ Ap)
{
    int p = blockIdx.x * 256 + threadIdx.x;    // (mstrip, kstep, ln)
    const int ln = p & 63; p >>= 6;
    const int kstep = p % AKSTEPS;
    const int strip = p / AKSTEPS;             // 0..15
    const int b = strip * 32 + (ln & 31);
    const int kb0 = kstep * 16 + (ln >> 5) * 8;
    const int blk = kb0 >> 9, bk0 = kb0 & 511;
    f16 out[8];
    #pragma unroll
    for (int j = 0; j < 8; ++j) {
        const int bk = bk0 + j;
        float v = (bk < DD) ? S[(size_t)b * DD + bk] : 0.f;
        f16 hi = (f16)v;
        out[j] = (blk == 1) ? (f16)(v - (float)hi) : hi;
    }
    *(uint4*)(Ap + ((size_t)(strip * AKSTEPS + kstep) * 64 + ln) * 8) = *(uint4*)out;
}

// ---------------------------------------------------------------------------
// Device-wide two-level barrier (once per 8-iter WINDOW only). Monotone,
// relaxed AGENT atomics. 32 groups of 8 blocks: bar[g*16] (64B apart),
// bar[512] root (32 arrivals), bar[528] generation.
// ---------------------------------------------------------------------------
__device__ __forceinline__ void grid_sync(unsigned* bar, unsigned e)
{
    __syncthreads();
    if (threadIdx.x == 0) {
        unsigned* gcnt = bar + ((blockIdx.x >> 3) << 4);
        unsigned* root = bar + 512;
        unsigned* gen  = bar + 528;
        unsigned a = __hip_atomic_fetch_add(gcnt, 1u, __ATOMIC_RELAXED,
                                            __HIP_MEMORY_SCOPE_AGENT);
        if (a == e * 8u + 7u) {
            unsigned r = __hip_atomic_fetch_add(root, 1u, __ATOMIC_RELAXED,
                                                __HIP_MEMORY_SCOPE_AGENT);
            if (r == e * 32u + 31u) {
                __hip_atomic_store(gen, e + 1u, __ATOMIC_RELAXED,
                                   __HIP_MEMORY_SCOPE_AGENT);
            } else {
                while (__hip_atomic_load(gen, __ATOMIC_RELAXED,
                                         __HIP_MEMORY_SCOPE_AGENT) <= e)
                    __builtin_amdgcn_s_sleep(1);
            }
        } else {
            while (__hip_atomic_load(gen, __ATOMIC_RELAXED,
                                     __HIP_MEMORY_SCOPE_AGENT) <= e)
                __builtin_amdgcn_s_sleep(1);
        }
    }
    __syncthreads();
}

// ---------------------------------------------------------------------------
// Persistent fused kernel, 256 blocks x 512 threads (8 waves = m-half x
// K-quarter). Block = 64 rows x 2 slabs x full K.
// Per iter: prefill B ring | group wait | stage Ah chunk (64KB) + issue Al
// loads early | phase-H MFMA (wk in {kq*8..}+{64+kq*8..}, 16 ksteps/wave) |
// restage Al | phase-L MFMA (8 ksteps/wave) | Ct 4-round kq combine
// (serialized plain writes -- LDS atomicAdd combine measured 2.4x WORSE in
// R16/R17) | EW (h in regs) | pack (coalesced sc stores) | group signal.
// Grid sync + break scan every 8 iters (speculative, 8-deep h history ring).
// LDS 64KB time-multiplexed: A chunk during gemm; Ct[64][72] + hbufP +
// red/trig after (A dead).
// ---------------------------------------------------------------------------
__global__ __launch_bounds__(512, 2) void gru_persist(
    f16* __restrict__ ApB,                 // 2 buffers of APCNT
    const f16* __restrict__ Wp0, const f16* __restrict__ Wp1,
    const float* __restrict__ bih, const float* __restrict__ bhh,
    float* __restrict__ out, float* __restrict__ spart,  // [8][64] stride 64
    const float* __restrict__ bc, const int* __restrict__ rec,
    unsigned* __restrict__ bar, unsigned* __restrict__ garr,
    float* __restrict__ hist)
{
    const int bid = blockIdx.x;
    const int tid = threadIdx.x;
    const int rounds = min(64, rec[0]);
    if (rounds <= 0) return;               // uniform: no barriers entered
    const float thr = bc[0] * (float)NELEM;

    const int cg = bid & 31;               // col-group (d base = 16*cg)
    const int rg = bid >> 5;               // row-group (64 rows)
    const int wv = tid >> 6, ln = tid & 63;
    const int mh = wv >> 2;                // m-half (32 rows)
    const int kq = wv & 3;                 // K-quarter
    const int sb0 = cg * 2, sb1 = cg * 2 + 1;          // this block's slabs

    __shared__ __align__(16) char smem[65536];
    f16*      Alds  = (f16*)smem;                      // [2 sl][32 aks][64][8]
    float*    Ct    = (float*)smem;                    // [64][2 sl][4 g][9]
    unsigned* hbufP = (unsigned*)(smem + 20480);       // [64][17] hi|lo pack
    float*    red   = (float*)(smem + 24832);          // [8]
    int*      trig  = (int*)(smem + 24864);

    float h[2];                            // registered h state (own slots)
    h[0] = 0.0f; h[1] = 0.0f;

    f16* bufs0 = ApB;
    f16* bufs1 = ApB + APCNT;
    unsigned* gptr = garr + rg * 16;       // group counter (own 64B line)
    unsigned wep = 0;                      // grid-sync episode

    for (int t = 0; t < rounds; ++t) {
        const f16* Wb    = (t == 0) ? Wp0 : Wp1;
        const f16* Abase = (t & 1) ? bufs1 : bufs0;
        f16*       Apw   = (t & 1) ? bufs0 : bufs1;    // EW writes other buf
        const f16* Bb0   = Wb + (size_t)sb0 * WKSTEPS * 512 + (size_t)ln * 8;
        const f16* Bb1   = Wb + (size_t)sb1 * WKSTEPS * 512 + (size_t)ln * 8;

        // phase-H B ring prefill: wk = kq*8 + i (independent of Ap)
        uint4 rB0[8], rB1[8];
        #pragma unroll
        for (int i = 0; i < 8; ++i) {
            rB0[i] = *(const uint4*)(Bb0 + (size_t)(kq * 8 + i) * 512);
            rB1[i] = *(const uint4*)(Bb1 + (size_t)(kq * 8 + i) * 512);
        }
        // group wait: all 32 producers of our A rows finished EW(t-1)
        if (t > 0) {
            if (tid == 0) {
                while (__hip_atomic_load(gptr, __ATOMIC_RELAXED,
                                         __HIP_MEMORY_SCOPE_AGENT)
                       < 32u * (unsigned)t)
                    __builtin_amdgcn_s_sleep(1);
            }
            __syncthreads();
        }

        // stage chunk H (Ah: aks 0..31, strips 2rg,2rg+1): 8 x 16B sc / thr
        u32x4 av[8];
        #pragma unroll
        for (int i = 0; i < 8; ++i) {
            const int flat = tid + 512 * i;
            const int sl_ = flat >> 11, rem = flat & 2047;
            aload16i(av[i], Abase +
                ((size_t)((2 * rg + sl_) * AKSTEPS + (rem >> 6)) * 64
                 + (rem & 63)) * 8);
        }
        asm volatile("s_waitcnt vmcnt(0)" ::: "memory");
        __builtin_amdgcn_sched_barrier(0);
        #pragma unroll
        for (int i = 0; i < 8; ++i)
            *(u32x4*)(Alds + (size_t)(tid + 512 * i) * 8) = av[i];
        // issue chunk L (Al: aks 32..63) loads NOW: latency hides under
        // phase-H MFMA (registers held across the phase)
        #pragma unroll
        for (int i = 0; i < 8; ++i) {
            const int flat = tid + 512 * i;
            const int sl_ = flat >> 11, rem = flat & 2047;
            aload16i(av[i], Abase +
                ((size_t)((2 * rg + sl_) * AKSTEPS + 32 + (rem >> 6)) * 64
                 + (rem & 63)) * 8);
        }
        __syncthreads();

        // phase H: 16 ksteps/wave. wk = kq*8+ksl (ksl<8) or 64+kq*8+(ksl-8);
        // A kstep ka = kq*8 + (ksl&7) in both (Ah pairs with Wh and Wl).
        f32x16 acc0 = {}, acc1 = {};
        #pragma unroll
        for (int ksl = 0; ksl < 16; ++ksl) {
            const int ka = kq * 8 + (ksl & 7);
            f16x8 a = *(const f16x8*)(Alds + ((size_t)(mh * 32 + ka) * 512
                                              + (size_t)ln * 8));
            acc0 = __builtin_amdgcn_mfma_f32_32x32x16_f16(
                       a, *(f16x8*)&rB0[ksl & 7], acc0, 0, 0, 0);
            acc1 = __builtin_amdgcn_mfma_f32_32x32x16_f16(
                       a, *(f16x8*)&rB1[ksl & 7], acc1, 0, 0, 0);
            if (ksl < 8) {                 // refill slot ksl with wk=64+kq*8+ksl
                rB0[ksl] = *(const uint4*)(Bb0 + (size_t)(64 + kq * 8 + ksl) * 512);
                rB1[ksl] = *(const uint4*)(Bb1 + (size_t)(64 + kq * 8 + ksl) * 512);
            }
        }
        __syncthreads();                   // phase-H A reads done

        // restage chunk L into the same buffer
        asm volatile("s_waitcnt vmcnt(0)" ::: "memory");
        __builtin_amdgcn_sched_barrier(0);
        #pragma unroll
        for (int i = 0; i < 8; ++i)
            *(u32x4*)(Alds + (size_t)(tid + 512 * i) * 8) = av[i];
        // phase-L B ring prefill: wk = 32 + kq*8 + i
        #pragma unroll
        for (int i = 0; i < 8; ++i) {
            rB0[i] = *(const uint4*)(Bb0 + (size_t)(32 + kq * 8 + i) * 512);
            rB1[i] = *(const uint4*)(Bb1 + (size_t)(32 + kq * 8 + i) * 512);
        }
        __syncthreads();

        // phase L: 8 ksteps/wave (Al x Wh)
        #pragma unroll
        for (int ksl = 0; ksl < 8; ++ksl) {
            const int ka = kq * 8 + ksl;
            f16x8 a = *(const f16x8*)(Alds + ((size_t)(mh * 32 + ka) * 512
                                              + (size_t)ln * 8));
            acc0 = __builtin_amdgcn_mfma_f32_32x32x16_f16(
                       a, *(f16x8*)&rB0[ksl], acc0, 0, 0, 0);
            acc1 = __builtin_amdgcn_mfma_f32_32x32x16_f16(
                       a, *(f16x8*)&rB1[ksl], acc1, 0, 0, 0);
        }
        __syncthreads();                   // all MFMA done; A buffer dead

        // Ct combine, 4 serialized kq rounds (plain writes; fastest measured).
        // C/D layout: col=lane&31, row=(r&3)+8*(r>>2)+4*(lane>>5).
        // Ct addr = row*72 + sl*36 + g*9 + dd
        {
            const int q = ln & 31, g = q >> 3, dd = q & 7;
            #pragma unroll
            for (int k = 0; k < 4; ++k) {
                if (kq == k) {
                    #pragma unroll
                    for (int r = 0; r < 16; ++r) {
                        const int row = mh * 32 + (r & 3) + 8 * (r >> 2)
                                        + 4 * (ln >> 5);
                        float* c0 = Ct + row * 72 + g * 9 + dd;
                        float* c1 = c0 + 36;
                        if (k == 0) { *c0 = acc0[r];  *c1 = acc1[r]; }
                        else        { *c0 += acc0[r]; *c1 += acc1[r]; }
                    }
                }
                __syncthreads();
            }
        }

        // ---------------- EW phase (h in registers) -----------------------
        float* hw = hist + ((size_t)bid * 8 + (size_t)(t & 7)) * HSTRIDE;
        float psum = 0.0f;
        #pragma unroll
        for (int i = 0; i < 2; ++i) {
            const int idx = i * 512 + tid;     // 1024 (row, dl) pairs
            const int row = idx >> 4, dl = idx & 15;
            const int d = cg * 16 + dl;
            const int sl = dl >> 3, dd = dl & 7;
            float hnew = 0.0f;
            if (d < DD) {
                const float* cb = &Ct[row * 72 + sl * 36 + dd];
                float cr = cb[0], cz = cb[9], cin = cb[18], chn = cb[27];
                float r = fsigmoid(cr + bih[d] + bhh[d]);
                float z = fsigmoid(cz + bih[500 + d] + bhh[500 + d]);
                float inn = cin + bih[1000 + d];
                float hn  = bhh[1000 + d];
                float hp  = 0.0f;
                if (t > 0) { hn += chn; hp = h[i]; }
                float n = ftanh(inn + r * hn);
                hnew = (1.0f - z) * n + z * hp;
                psum += hnew;
            }
            h[i] = hnew;
            hw[idx] = hnew;                    // history ring (block-private)
            f16 hi = (f16)hnew;
            f16 lo = (f16)(hnew - (float)hi);
            union { f16 f[2]; unsigned u; } pk;
            pk.f[0] = hi; pk.f[1] = lo;
            hbufP[row * 17 + dl] = pk.u;       // pad-striped
        }
        // block reduce psum -> spart shard (cg&7)
        #pragma unroll
        for (int off = 32; off > 0; off >>= 1) psum += __shfl_down(psum, off, 64);
        if (ln == 0) red[wv] = psum;
        __syncthreads();                        // red + hbufP ready
        if (tid == 0) {
            float v = red[0] + red[1] + red[2] + red[3]
                    + red[4] + red[5] + red[6] + red[7];
            __hip_atomic_fetch_add(&spart[(size_t)(cg & 7) * 64 + t], v,
                                   __ATOMIC_RELAXED, __HIP_MEMORY_SCOPE_AGENT);
        }
        // pack Ap: (row 0..63, oct 0..1) -> d0 = cg*16 + oct*8.
        // hi kstep = cg, lo kstep = 32+cg, half = oct, strip = 2rg + row/32.
        if (tid < 128) {
            const int row = tid >> 1, oct = tid & 1;
            union { f16 a[8]; u32x4 v; } hiU, loU;
            #pragma unroll
            for (int j = 0; j < 8; ++j) {
                unsigned u = hbufP[row * 17 + oct * 8 + j];
                union { unsigned u; f16 f[2]; } pk; pk.u = u;
                hiU.a[j] = pk.f[0];
                loU.a[j] = pk.f[1];
            }
            const int strip = 2 * rg + (row >> 5), lm = row & 31;
            f16* dhi = Apw + ((size_t)(strip * AKSTEPS + cg)      * 64
                              + oct * 32 + lm) * 8;
            f16* dlo = Apw + ((size_t)(strip * AKSTEPS + 32 + cg) * 64
                              + oct * 32 + lm) * 8;
            astore16(dhi, hiU.v);
            astore16(dlo, loU.v);
        }
        asm volatile("s_waitcnt vmcnt(0)" ::: "memory");   // sc stores acked
        __syncthreads();
        if (tid == 0)
            __hip_atomic_fetch_add(gptr, 1u, __ATOMIC_RELAXED,
                                   __HIP_MEMORY_SCOPE_AGENT);

        // -------- window boundary: grid sync + break scan -----------------
        if (((t & 7) == 7) || (t == rounds - 1)) {
            grid_sync(bar, wep++);             // all spart(t' <= t) visible
            if (tid < 64) {                    // wave 0 scans the window
                const int cgl = tid & 7, ti = tid >> 3;
                const int tt = (t & ~7) + ti;
                float v = 0.f;
                if (tt <= t)
                    v = aload_f32(&spart[(size_t)cgl * 64 + tt]);
                v += __shfl_xor(v, 1, 64);
                v += __shfl_xor(v, 2, 64);
                v += __shfl_xor(v, 4, 64);
                bool hit = ((tid & 7) == 0) && (tt <= t) && (v > thr);
                unsigned long long m = __ballot(hit);
                if (tid == 0)
                    trig[0] = m ? (int)((__ffsll((long long)m) - 1) >> 3) : -1;
            }
            __syncthreads();
            const int w0 = trig[0];
            if (w0 >= 0) {                     // break fired at ts (uniform)
                const int ts = (t & ~7) + w0;
                const float* hs = hist
                    + ((size_t)bid * 8 + (size_t)(ts & 7)) * HSTRIDE;
                #pragma unroll
                for (int i = 0; i < 2; ++i) {
                    const int idx = i * 512 + tid;
                    const int row = idx >> 4, dl = idx & 15;
                    const int d = cg * 16 + dl;
                    if (d < DD)
                        out[(size_t)(rg * 64 + row) * DD + d] = hs[idx];
                }
                return;
            }
        }
    }

    // no trigger: final output from registered h
    #pragma unroll
    for (int i = 0; i < 2; ++i) {
        const int idx = i * 512 + tid;
        const int row = idx >> 4, dl = idx & 15;
        const int d = cg * 16 + dl;
        if (d < DD)
            out[(size_t)(rg * 64 + row) * DD + d] = h[i];
    }
}

extern "C" void kernel_launch(void* const* d_in, const int* in_sizes, int n_in,
                              void* d_out, int out_size, void* d_ws, size_t ws_size,
                              hipStream_t stream)
{
    const float* state = (const float*)d_in[0];
    const float* Wih   = (const float*)d_in[1];
    const float* Whh   = (const float*)d_in[2];
    const float* bih   = (const float*)d_in[3];
    const float* bhh   = (const float*)d_in[4];
    const float* bc    = (const float*)d_in[5];
    const int*   rec   = (const int*)d_in[6];

    char* ws = (char*)d_ws;
    float*    spart = (float*)ws;                   // 2 KB (8 shards x 64 t)
    unsigned* bar   = (unsigned*)(ws + 2048);       // 4 KB (32 groups + root)
    unsigned* garr  = (unsigned*)(ws + 6144);       // 1 KB (8 rg x 64B)
    f16*   ApB   = (f16*)(ws + 8192);               // 2 x 1 MB
    f16*   Wp0   = ApB + 2 * APCNT;                 // 6.29 MB
    f16*   Wp1   = Wp0 + WPCNT;                     // 6.29 MB
    float* hist  = (float*)(Wp1 + WPCNT);           // 8 MB (256x8x1024 f32)
    float* out   = (float*)d_out;

    hipMemsetAsync(ws, 0, 8192, stream);            // spart + bar + garr
    // rec==0 robustness: output = state if no iteration runs
    hipMemcpyAsync(out, state, (size_t)NELEM * sizeof(float),
                   hipMemcpyDeviceToDevice, stream);

    conv_w<<<dim3(NSTRIPS * WKSTEPS * 64 / 256), 256, 0, stream>>>(Wih, Whh, Wp0, Wp1);
    conv_a<<<dim3(MSTRIPS * AKSTEPS * 64 / 256), 256, 0, stream>>>(state, ApB);

    gru_persist<<<dim3(NBLK), dim3(512), 0, stream>>>(
        ApB, Wp0, Wp1, bih, bhh, out, spart, bc, rec, bar, garr, hist);
}